// Round 2
// baseline (765.471 us; speedup 1.0000x reference)
//
#include <hip/hip_runtime.h>

typedef unsigned short u16;
typedef unsigned int u32;
typedef __bf16 bf16x8 __attribute__((ext_vector_type(8)));
typedef float f32x4 __attribute__((ext_vector_type(4)));

// ---------- helpers ----------
__device__ __forceinline__ u16 f2bf(float f) {
  union { float f; u32 u; } v; v.f = f;
  u32 r = v.u + 0x7fffu + ((v.u >> 16) & 1u);   // RNE
  return (u16)(r >> 16);
}

__device__ __forceinline__ bf16x8 ldb128(const u16* p) {
  return *reinterpret_cast<const bf16x8*>(p);
}

__device__ __forceinline__ f32x4 mfma16(bf16x8 a, bf16x8 b, f32x4 c) {
  return __builtin_amdgcn_mfma_f32_16x16x32_bf16(a, b, c, 0, 0, 0);
}

typedef const __attribute__((address_space(1))) u32* gas_p;
typedef __attribute__((address_space(3))) u32* las_p;
// async global->LDS, 16B per lane; lds dst is wave-uniform base + lane*16B
__device__ __forceinline__ void gld_lds16(const void* g, void* l) {
  __builtin_amdgcn_global_load_lds((gas_p)(unsigned long long)g,
                                   (las_p)(u32)(unsigned long long)l, 16, 0, 0);
}

// ---------- convert f32 -> bf16 (vectorized) ----------
__global__ __launch_bounds__(256) void cvt_f32_bf16(const float4* __restrict__ in,
                                                    uint2* __restrict__ out) {
  int i = blockIdx.x * 256 + threadIdx.x;
  float4 v = in[i];
  uint2 r;
  r.x = (u32)f2bf(v.x) | ((u32)f2bf(v.y) << 16);
  r.y = (u32)f2bf(v.z) | ((u32)f2bf(v.w) << 16);
  out[i] = r;
}

// ---------- transpose + convert: in[R][C] f32 -> out[C][R] bf16 ----------
__global__ __launch_bounds__(256) void transp_cvt(const float* __restrict__ in,
                                                  u16* __restrict__ out, int R, int C) {
  __shared__ float tile[32][33];
  int n0 = blockIdx.x * 32, k0 = blockIdx.y * 32;
  int tx = threadIdx.x, ty = threadIdx.y;   // block (32,8)
#pragma unroll
  for (int i = 0; i < 32; i += 8) tile[ty + i][tx] = in[(k0 + ty + i) * C + n0 + tx];
  __syncthreads();
#pragma unroll
  for (int i = 0; i < 32; i += 8) out[(n0 + ty + i) * R + k0 + tx] = f2bf(tile[tx][ty + i]);
}

// ---------- GEMM: C = A[M][K] @ Bt[N][K]^T, 128x128 tile, m97 structure ----------
// mode 0: QKV epilogue (RoPE on Q/K, V transposed), mode 1: plain f32 store
__global__ __launch_bounds__(256) void gemm_bf16(
    const u16* __restrict__ A, const u16* __restrict__ Bt,
    int M, int N, int K, int mode,
    const float* __restrict__ cosb, const float* __restrict__ sinb,
    u16* __restrict__ Qb, u16* __restrict__ Kb, u16* __restrict__ Vt,
    float* __restrict__ outf) {
  __shared__ u16 As[128 * 32];
  __shared__ u16 Bs[128 * 32];
  const int tid = threadIdx.x;
  const int wv = tid >> 6, lane = tid & 63;
  const int c = lane & 15, g = lane >> 4;
  const int m0 = blockIdx.y * 128, n0 = blockIdx.x * 128;
  const int wr = wv >> 1, wc = wv & 1;

  f32x4 acc[4][4] = {};

  const int ar = wv * 16 + (lane >> 2);      // staging row (within 64-row half)
  const int ak = (lane & 3) * 8;             // staging col (elements)
  u16* ldsA0 = &As[(wv * 16) * 32];
  u16* ldsA1 = &As[(64 + wv * 16) * 32];
  u16* ldsB0 = &Bs[(wv * 16) * 32];
  u16* ldsB1 = &Bs[(64 + wv * 16) * 32];
  const u16* gA  = A  + (m0 + ar) * K + ak;
  const u16* gA1 = gA + 64 * K;
  const u16* gB  = Bt + (n0 + ar) * K + ak;
  const u16* gB1 = gB + 64 * K;

  for (int kt = 0; kt < K; kt += 32) {
    gld_lds16(gA + kt, ldsA0);
    gld_lds16(gA1 + kt, ldsA1);
    gld_lds16(gB + kt, ldsB0);
    gld_lds16(gB1 + kt, ldsB1);
    __syncthreads();    // compiler drains vmcnt before s_barrier
    bf16x8 af[4], bf[4];
#pragma unroll
    for (int i = 0; i < 4; i++) af[i] = ldb128(&As[(wr * 64 + i * 16 + c) * 32 + g * 8]);
#pragma unroll
    for (int i = 0; i < 4; i++) bf[i] = ldb128(&Bs[(wc * 64 + i * 16 + c) * 32 + g * 8]);
#pragma unroll
    for (int i = 0; i < 4; i++)
#pragma unroll
      for (int j = 0; j < 4; j++) acc[i][j] = mfma16(af[i], bf[j], acc[i][j]);
    __syncthreads();
  }

  const float inv_sqrt_hd = 0.08838834764831845f;
#pragma unroll
  for (int i = 0; i < 4; i++) {
#pragma unroll
    for (int j = 0; j < 4; j++) {
      const int ncol = n0 + wc * 64 + j * 16 + c;
#pragma unroll
      for (int r = 0; r < 4; r++) {
        const int m = m0 + wr * 64 + i * 16 + g * 4 + r;
        float val = acc[i][j][r];
        if (mode == 1) {
          outf[m * N + ncol] = val;
          continue;
        }
        const int s = m & 2047;
        if (ncol < 2048) {              // Q: RoPE + 1/sqrt(hd), bf16
          const int d = ncol & 127;
          float ct = cosb[s * 128 + d], st = sinb[s * 128 + d];
          float pr = __shfl_xor(val, 1, 64);
          float rot = (ncol & 1) ? pr : -pr;
          Qb[m * 2048 + ncol] = f2bf((val * ct + rot * st) * inv_sqrt_hd);
        } else if (ncol < 2560) {       // K: RoPE, bf16
          const int d = ncol & 127;
          float ct = cosb[s * 128 + d], st = sinb[s * 128 + d];
          float pr = __shfl_xor(val, 1, 64);
          float rot = (ncol & 1) ? pr : -pr;
          Kb[m * 512 + (ncol - 2048)] = f2bf(val * ct + rot * st);
        } else {                        // V: store transposed Vt[bkvh*128+d][s]
          const int bb = m >> 11;
          Vt[(bb * 512 + (ncol - 2560)) * 2048 + s] = f2bf(val);
        }
      }
    }
  }
}

// ---------- flash attention (causal, GQA). 4 waves x 16 q-rows, KV tile 64 ----------
__global__ __launch_bounds__(256) void attn_fwd(
    const u16* __restrict__ Qb, const u16* __restrict__ Kb,
    const u16* __restrict__ Vt, u16* __restrict__ attnb) {
  const int tid = threadIdx.x;
  const int wv = tid >> 6, lane = tid & 63;
  const int c = lane & 15, g = lane >> 4;
  const int qt = blockIdx.x, h = blockIdx.y, b = blockIdx.z;
  const int kvh = h >> 2;
  const int q = qt * 64 + wv * 16 + c;    // this lane's q row (col of S^T frags)

  __shared__ u16 Pl[4][16][80];           // per-wave P tile [q][k], +16 pad

  bf16x8 qf[4];
  const u16* qptr = Qb + ((b << 11) + q) * 2048 + h * 128 + g * 8;
#pragma unroll
  for (int dc = 0; dc < 4; dc++) qf[dc] = ldb128(qptr + dc * 32);

  f32x4 oacc[8] = {};
  float m_run = -1e30f, l_run = 0.f;

  const u16* Kbase = Kb + (b << 11) * 512 + kvh * 128 + g * 8;
  const u16* Vbase = Vt + (b * 512 + kvh * 128 + c) * 2048 + g * 8;

  for (int kt = 0; kt <= qt; kt++) {
    const int k0 = kt * 64;
    // S^T = K @ Q^T : T[key][q], col=lane&15=q, row=(g*4+r)+16*kf=key
    f32x4 t[4] = {};
#pragma unroll
    for (int kf = 0; kf < 4; kf++) {
      const u16* kp = Kbase + (k0 + kf * 16 + c) * 512;
#pragma unroll
      for (int dc = 0; dc < 4; dc++) t[kf] = mfma16(ldb128(kp + dc * 32), qf[dc], t[kf]);
    }
    if (kt == qt) {                       // causal mask on diagonal tile
#pragma unroll
      for (int kf = 0; kf < 4; kf++)
#pragma unroll
        for (int r = 0; r < 4; r++)
          if (k0 + kf * 16 + g * 4 + r > q) t[kf][r] = -1e30f;
    }
    // online softmax (row over keys = per-lane 16 vals + xor16/32 across groups)
    float pmax = -1e30f;
#pragma unroll
    for (int kf = 0; kf < 4; kf++)
#pragma unroll
      for (int r = 0; r < 4; r++) pmax = fmaxf(pmax, t[kf][r]);
    pmax = fmaxf(pmax, __shfl_xor(pmax, 16, 64));
    pmax = fmaxf(pmax, __shfl_xor(pmax, 32, 64));
    const float mnew = fmaxf(m_run, pmax);
    const float scale = __expf(m_run - mnew);
    float psum = 0.f;
#pragma unroll
    for (int kf = 0; kf < 4; kf++) {
#pragma unroll
      for (int r = 0; r < 4; r++) {
        float p = __expf(t[kf][r] - mnew);
        psum += p;
        Pl[wv][c][kf * 16 + g * 4 + r] = f2bf(p);
      }
    }
    psum += __shfl_xor(psum, 16, 64);
    psum += __shfl_xor(psum, 32, 64);
    l_run = l_run * scale + psum;
    m_run = mnew;
#pragma unroll
    for (int df = 0; df < 8; df++) oacc[df] *= scale;
    // PV: O^T[d][q] += Vt[d][s] * P^T[s][q]
    bf16x8 pb0 = ldb128(&Pl[wv][c][g * 8]);
    bf16x8 pb1 = ldb128(&Pl[wv][c][32 + g * 8]);
#pragma unroll
    for (int df = 0; df < 8; df++) {
      const u16* vp = Vbase + df * 16 * 2048 + k0;
      oacc[df] = mfma16(ldb128(vp), pb0, oacc[df]);
      oacc[df] = mfma16(ldb128(vp + 32), pb1, oacc[df]);
    }
  }

  const float rinv = 1.f / l_run;
  const int obase = ((b << 11) + q) * 2048 + h * 128;
#pragma unroll
  for (int df = 0; df < 8; df++)
#pragma unroll
    for (int r = 0; r < 4; r++)
      attnb[obase + df * 16 + g * 4 + r] = f2bf(oacc[df][r] * rinv);
}

// ---------- launch ----------
extern "C" void kernel_launch(void* const* d_in, const int* in_sizes, int n_in,
                              void* d_out, int out_size, void* d_ws, size_t ws_size,
                              hipStream_t stream) {
  const float* X    = (const float*)d_in[0];  // (2,2048,2048)
  const float* cosb = (const float*)d_in[1];  // (2048,128)
  const float* sinb = (const float*)d_in[2];
  const float* Wq   = (const float*)d_in[3];  // (2048,2048)
  const float* Wk   = (const float*)d_in[4];  // (2048,512)
  const float* Wv   = (const float*)d_in[5];
  const float* Wo   = (const float*)d_in[6];  // (2048,2048)

  char* ws = (char*)d_ws;
  u16* Xb    = (u16*)(ws);                       // 4096x2048 bf16 : 16 MB
  u16* Wt    = (u16*)(ws + 16777216);            // 3072x2048 bf16 : 12 MB (Wq^T|Wk^T|Wv^T)
  u16* Wot   = (u16*)(ws + 29360128);            // 2048x2048 bf16 : 8 MB
  u16* Qb    = (u16*)(ws + 37748736);            // 4096x2048 bf16 : 16 MB
  u16* Kb    = (u16*)(ws + 54525952);            // 4096x512  bf16 : 4 MB
  u16* Vt    = (u16*)(ws + 58720256);            // 1024x2048 bf16 : 4 MB  [b*512+kvh*128+d][s]
  u16* attnb = Xb;                               // alias: Xb dead after QKV GEMM
  // total 62914560 B (60 MB) of d_ws

  // 1) convert hidden to bf16
  cvt_f32_bf16<<<dim3(8192), dim3(256), 0, stream>>>((const float4*)X, (uint2*)Xb);
  // 2) transpose+convert weights -> [N][K] bf16
  transp_cvt<<<dim3(64, 64), dim3(32, 8), 0, stream>>>(Wq, Wt, 2048, 2048);
  transp_cvt<<<dim3(16, 64), dim3(32, 8), 0, stream>>>(Wk, Wt + 2048 * 2048, 2048, 512);
  transp_cvt<<<dim3(16, 64), dim3(32, 8), 0, stream>>>(Wv, Wt + 2560 * 2048, 2048, 512);
  transp_cvt<<<dim3(64, 64), dim3(32, 8), 0, stream>>>(Wo, Wot, 2048, 2048);
  // 3) fused QKV GEMM + RoPE epilogue
  gemm_bf16<<<dim3(24, 32), dim3(256), 0, stream>>>(Xb, Wt, 4096, 3072, 2048, 0,
                                                    cosb, sinb, Qb, Kb, Vt, nullptr);
  // 4) causal GQA flash attention
  attn_fwd<<<dim3(32, 16, 2), dim3(256), 0, stream>>>(Qb, Kb, Vt, attnb);
  // 5) output GEMM -> f32 d_out
  gemm_bf16<<<dim3(16, 32), dim3(256), 0, stream>>>(attnb, Wot, 4096, 2048, 2048, 1,
                                                    nullptr, nullptr, nullptr, nullptr, nullptr,
                                                    (float*)d_out);
}

// Round 3
// 444.752 us; speedup vs baseline: 1.7211x; 1.7211x over previous
//
#include <hip/hip_runtime.h>

typedef unsigned short u16;
typedef unsigned int u32;
typedef __bf16 bf16x8 __attribute__((ext_vector_type(8)));
typedef float f32x4 __attribute__((ext_vector_type(4)));

// ---------- helpers ----------
__device__ __forceinline__ u16 f2bf(float f) {
  union { float f; u32 u; } v; v.f = f;
  u32 r = v.u + 0x7fffu + ((v.u >> 16) & 1u);   // RNE
  return (u16)(r >> 16);
}

__device__ __forceinline__ bf16x8 ldb128(const u16* p) {
  return *reinterpret_cast<const bf16x8*>(p);
}

__device__ __forceinline__ f32x4 mfma16(bf16x8 a, bf16x8 b, f32x4 c) {
  return __builtin_amdgcn_mfma_f32_16x16x32_bf16(a, b, c, 0, 0, 0);
}

typedef const __attribute__((address_space(1))) u32* gas_p;
typedef __attribute__((address_space(3))) u32* las_p;
// async global->LDS, 16B per lane; lds dst is wave-uniform base + lane*16B
__device__ __forceinline__ void gld_lds16(const void* g, void* l) {
  __builtin_amdgcn_global_load_lds((gas_p)(unsigned long long)g,
                                   (las_p)(u32)(unsigned long long)l, 16, 0, 0);
}

// ---------- convert f32 -> bf16 (vectorized) ----------
__global__ __launch_bounds__(256) void cvt_f32_bf16(const float4* __restrict__ in,
                                                    uint2* __restrict__ out) {
  int i = blockIdx.x * 256 + threadIdx.x;
  float4 v = in[i];
  uint2 r;
  r.x = (u32)f2bf(v.x) | ((u32)f2bf(v.y) << 16);
  r.y = (u32)f2bf(v.z) | ((u32)f2bf(v.w) << 16);
  out[i] = r;
}

// ---------- transpose + convert: in[R][C] f32 -> out[C][R] bf16 ----------
__global__ __launch_bounds__(256) void transp_cvt(const float* __restrict__ in,
                                                  u16* __restrict__ out, int R, int C) {
  __shared__ float tile[32][33];
  int n0 = blockIdx.x * 32, k0 = blockIdx.y * 32;
  int tx = threadIdx.x, ty = threadIdx.y;   // block (32,8)
#pragma unroll
  for (int i = 0; i < 32; i += 8) tile[ty + i][tx] = in[(k0 + ty + i) * C + n0 + tx];
  __syncthreads();
#pragma unroll
  for (int i = 0; i < 32; i += 8) out[(n0 + ty + i) * R + k0 + tx] = f2bf(tile[tx][ty + i]);
}

// ---------- GEMM: C = A[M][K] @ Bt[N][K]^T, 128x128 tile, m97 structure ----------
// mode 0: QKV epilogue (RoPE on Q/K, V transposed), mode 1: plain f32 store
__global__ __launch_bounds__(256) void gemm_bf16(
    const u16* __restrict__ A, const u16* __restrict__ Bt,
    int M, int N, int K, int mode,
    const float* __restrict__ cosb, const float* __restrict__ sinb,
    u16* __restrict__ Qb, u16* __restrict__ Kb, u16* __restrict__ Vt,
    float* __restrict__ outf) {
  __shared__ u16 As[128 * 32];
  __shared__ u16 Bs[128 * 32];
  const int tid = threadIdx.x;
  const int wv = tid >> 6, lane = tid & 63;
  const int c = lane & 15, g = lane >> 4;
  const int m0 = blockIdx.y * 128, n0 = blockIdx.x * 128;
  const int wr = wv >> 1, wc = wv & 1;

  f32x4 acc[4][4] = {};

  const int ar = wv * 16 + (lane >> 2);      // staging row (within 64-row half)
  const int ak = (lane & 3) * 8;             // staging col (elements)
  u16* ldsA0 = &As[(wv * 16) * 32];
  u16* ldsA1 = &As[(64 + wv * 16) * 32];
  u16* ldsB0 = &Bs[(wv * 16) * 32];
  u16* ldsB1 = &Bs[(64 + wv * 16) * 32];
  const u16* gA  = A  + (m0 + ar) * K + ak;
  const u16* gA1 = gA + 64 * K;
  const u16* gB  = Bt + (n0 + ar) * K + ak;
  const u16* gB1 = gB + 64 * K;

  for (int kt = 0; kt < K; kt += 32) {
    gld_lds16(gA + kt, ldsA0);
    gld_lds16(gA1 + kt, ldsA1);
    gld_lds16(gB + kt, ldsB0);
    gld_lds16(gB1 + kt, ldsB1);
    __syncthreads();    // compiler drains vmcnt before s_barrier
    bf16x8 af[4], bf[4];
#pragma unroll
    for (int i = 0; i < 4; i++) af[i] = ldb128(&As[(wr * 64 + i * 16 + c) * 32 + g * 8]);
#pragma unroll
    for (int i = 0; i < 4; i++) bf[i] = ldb128(&Bs[(wc * 64 + i * 16 + c) * 32 + g * 8]);
#pragma unroll
    for (int i = 0; i < 4; i++)
#pragma unroll
      for (int j = 0; j < 4; j++) acc[i][j] = mfma16(af[i], bf[j], acc[i][j]);
    __syncthreads();
  }

  const float inv_sqrt_hd = 0.08838834764831845f;
#pragma unroll
  for (int i = 0; i < 4; i++) {
#pragma unroll
    for (int j = 0; j < 4; j++) {
      const int ncol = n0 + wc * 64 + j * 16 + c;
#pragma unroll
      for (int r = 0; r < 4; r++) {
        const int m = m0 + wr * 64 + i * 16 + g * 4 + r;
        float val = acc[i][j][r];
        if (mode == 1) {
          outf[m * N + ncol] = val;
          continue;
        }
        const int s = m & 2047;
        if (ncol < 2048) {              // Q: RoPE + 1/sqrt(hd), bf16
          const int d = ncol & 127;
          float ct = cosb[s * 128 + d], st = sinb[s * 128 + d];
          float pr = __shfl_xor(val, 1, 64);
          float rot = (ncol & 1) ? pr : -pr;
          Qb[m * 2048 + ncol] = f2bf((val * ct + rot * st) * inv_sqrt_hd);
        } else if (ncol < 2560) {       // K: RoPE, bf16
          const int d = ncol & 127;
          float ct = cosb[s * 128 + d], st = sinb[s * 128 + d];
          float pr = __shfl_xor(val, 1, 64);
          float rot = (ncol & 1) ? pr : -pr;
          Kb[m * 512 + (ncol - 2048)] = f2bf(val * ct + rot * st);
        } else {                        // V: store transposed Vt[bkvh*128+d][s]
          const int bb = m >> 11;
          Vt[(bb * 512 + (ncol - 2560)) * 2048 + s] = f2bf(val);
        }
      }
    }
  }
}

// ---------- flash attention v2: LDS-staged K/V (XOR-swizzled), causal, GQA ----------
// 4 waves x 16 q-rows (QBLK=64), KV tile 64. K/V staged cooperatively via
// global_load_lds with pre-swizzled per-lane SOURCE (linear LDS dest, rule 21).
__global__ __launch_bounds__(256) void attn_fwd(
    const u16* __restrict__ Qb, const u16* __restrict__ Kb,
    const u16* __restrict__ Vt, u16* __restrict__ attnb) {
  __shared__ u16 Ks[64 * 128];    // [key][d], rows XOR-swizzled: LDS[r][o]=G[r][o^((r&7)<<4)]
  __shared__ u16 Vs[128 * 64];    // [d][key], same swizzle
  __shared__ u16 Pl[4][16 * 64];  // per-wave P [q][k], same swizzle
  const int tid = threadIdx.x;
  const int wv = tid >> 6, lane = tid & 63;
  const int c = lane & 15, g = lane >> 4;
  const int qt = 31 - (int)blockIdx.x;         // heavy blocks dispatch first
  const int h = blockIdx.y, b = blockIdx.z;
  const int kvh = h >> 2;
  const int q = qt * 64 + wv * 16 + c;         // this lane's q row (col of S^T frags)
  const int swz = (c & 7) << 4;                // byte-XOR for this lane's frag rows

  bf16x8 qf[4];
  const u16* qptr = Qb + ((b << 11) + q) * 2048 + h * 128 + g * 8;
#pragma unroll
  for (int dc = 0; dc < 4; dc++) qf[dc] = ldb128(qptr + dc * 32);

  f32x4 oacc[8] = {};
  float m_run = -1e30f, l_run = 0.f;

  // staging geometry (per lane)
  const int krow = wv * 16 + g;                // + i*4 ; K chunk rows (4 lanes' g x 16 c)
  const int vrow = wv * 32 + (lane >> 3);      // + i*8 ; V chunk rows
  const u16* Kg = Kb + kvh * 128;              // + s*512
  const u16* Vg = Vt + (b * 512 + kvh * 128) * 2048;

  for (int kt = 0; kt <= qt; kt++) {
    const int k0 = kt * 64;
    // ---- stage K tile [64][128] : 16 chunks of 1KB, 4 per wave ----
#pragma unroll
    for (int i = 0; i < 4; i++) {
      const int r = krow + i * 4;
      gld_lds16(Kg + ((long)(b * 2048 + k0 + r)) * 512 + ((c ^ (r & 7)) * 8),
                &Ks[(wv * 4 + i) * 512]);
    }
    // ---- stage V tile [128][64] ----
#pragma unroll
    for (int i = 0; i < 4; i++) {
      const int r = vrow + i * 8;
      gld_lds16(Vg + (long)r * 2048 + k0 + (((lane & 7) ^ (r & 7)) * 8),
                &Vs[(wv * 4 + i) * 512]);
    }
    __syncthreads();                            // drains vmcnt before barrier

    // ---- S^T = K @ Q^T : col=lane&15=q, row(key)=kf*16+g*4+r ----
    f32x4 t[4] = {};
#pragma unroll
    for (int kf = 0; kf < 4; kf++) {
#pragma unroll
      for (int dc = 0; dc < 4; dc++) {
        const bf16x8 kfr = ldb128(&Ks[(kf * 16 + c) * 128 + (((dc * 64 + g * 16) ^ swz) >> 1)]);
        t[kf] = mfma16(kfr, qf[dc], t[kf]);
      }
    }
    if (kt == qt) {                             // causal mask on diagonal tile
#pragma unroll
      for (int kf = 0; kf < 4; kf++)
#pragma unroll
        for (int r = 0; r < 4; r++)
          if (k0 + kf * 16 + g * 4 + r > q) t[kf][r] = -1e30f;
    }
    // ---- online softmax: per-lane 16 keys + xor16/32 across g-groups ----
    float pmax = -1e30f;
#pragma unroll
    for (int kf = 0; kf < 4; kf++)
#pragma unroll
      for (int r = 0; r < 4; r++) pmax = fmaxf(pmax, t[kf][r]);
    pmax = fmaxf(pmax, __shfl_xor(pmax, 16, 64));
    pmax = fmaxf(pmax, __shfl_xor(pmax, 32, 64));
    const float mnew = fmaxf(m_run, pmax);
    const float scale = __expf(m_run - mnew);
    float psum = 0.f;
#pragma unroll
    for (int kf = 0; kf < 4; kf++) {
      float p0 = __expf(t[kf][0] - mnew), p1 = __expf(t[kf][1] - mnew);
      float p2 = __expf(t[kf][2] - mnew), p3 = __expf(t[kf][3] - mnew);
      psum += (p0 + p1) + (p2 + p3);
      u32* pw = (u32*)&Pl[wv][c * 64 + (((kf * 32 + g * 8) ^ swz) >> 1)];
      pw[0] = (u32)f2bf(p0) | ((u32)f2bf(p1) << 16);
      pw[1] = (u32)f2bf(p2) | ((u32)f2bf(p3) << 16);
    }
    psum += __shfl_xor(psum, 16, 64);
    psum += __shfl_xor(psum, 32, 64);
    l_run = l_run * scale + psum;
    m_run = mnew;
#pragma unroll
    for (int df = 0; df < 8; df++) oacc[df] *= scale;

    // ---- PV: O^T[d][q] += Vs[d][k] * P^T[k][q] ----
    const bf16x8 pb0 = ldb128(&Pl[wv][c * 64 + (((g * 16) ^ swz) >> 1)]);
    const bf16x8 pb1 = ldb128(&Pl[wv][c * 64 + (((64 + g * 16) ^ swz) >> 1)]);
#pragma unroll
    for (int df = 0; df < 8; df++) {
      const int vb = (df * 16 + c) * 64;
      oacc[df] = mfma16(ldb128(&Vs[vb + (((g * 16) ^ swz) >> 1)]), pb0, oacc[df]);
      oacc[df] = mfma16(ldb128(&Vs[vb + (((64 + g * 16) ^ swz) >> 1)]), pb1, oacc[df]);
    }
    __syncthreads();                            // protect Ks/Vs before next stage
  }

  const float rinv = 1.f / l_run;
  const int obase = ((b << 11) + q) * 2048 + h * 128;
#pragma unroll
  for (int df = 0; df < 8; df++)
#pragma unroll
    for (int r = 0; r < 4; r++)
      attnb[obase + df * 16 + g * 4 + r] = f2bf(oacc[df][r] * rinv);
}

// ---------- launch ----------
extern "C" void kernel_launch(void* const* d_in, const int* in_sizes, int n_in,
                              void* d_out, int out_size, void* d_ws, size_t ws_size,
                              hipStream_t stream) {
  const float* X    = (const float*)d_in[0];  // (2,2048,2048)
  const float* cosb = (const float*)d_in[1];  // (2048,128)
  const float* sinb = (const float*)d_in[2];
  const float* Wq   = (const float*)d_in[3];  // (2048,2048)
  const float* Wk   = (const float*)d_in[4];  // (2048,512)
  const float* Wv   = (const float*)d_in[5];
  const float* Wo   = (const float*)d_in[6];  // (2048,2048)

  char* ws = (char*)d_ws;
  u16* Xb    = (u16*)(ws);                       // 4096x2048 bf16 : 16 MB
  u16* Wt    = (u16*)(ws + 16777216);            // 3072x2048 bf16 : 12 MB (Wq^T|Wk^T|Wv^T)
  u16* Wot   = (u16*)(ws + 29360128);            // 2048x2048 bf16 : 8 MB
  u16* Qb    = (u16*)(ws + 37748736);            // 4096x2048 bf16 : 16 MB
  u16* Kb    = (u16*)(ws + 54525952);            // 4096x512  bf16 : 4 MB
  u16* Vt    = (u16*)(ws + 58720256);            // 1024x2048 bf16 : 4 MB  [b*512+kvh*128+d][s]
  u16* attnb = Xb;                               // alias: Xb dead after QKV GEMM
  // total 62914560 B (60 MB) of d_ws

  // 1) convert hidden to bf16
  cvt_f32_bf16<<<dim3(8192), dim3(256), 0, stream>>>((const float4*)X, (uint2*)Xb);
  // 2) transpose+convert weights -> [N][K] bf16
  transp_cvt<<<dim3(64, 64), dim3(32, 8), 0, stream>>>(Wq, Wt, 2048, 2048);
  transp_cvt<<<dim3(16, 64), dim3(32, 8), 0, stream>>>(Wk, Wt + 2048 * 2048, 2048, 512);
  transp_cvt<<<dim3(16, 64), dim3(32, 8), 0, stream>>>(Wv, Wt + 2560 * 2048, 2048, 512);
  transp_cvt<<<dim3(64, 64), dim3(32, 8), 0, stream>>>(Wo, Wot, 2048, 2048);
  // 3) fused QKV GEMM + RoPE epilogue
  gemm_bf16<<<dim3(24, 32), dim3(256), 0, stream>>>(Xb, Wt, 4096, 3072, 2048, 0,
                                                    cosb, sinb, Qb, Kb, Vt, nullptr);
  // 4) causal GQA flash attention
  attn_fwd<<<dim3(32, 16, 2), dim3(256), 0, stream>>>(Qb, Kb, Vt, attnb);
  // 5) output GEMM -> f32 d_out
  gemm_bf16<<<dim3(16, 32), dim3(256), 0, stream>>>(attnb, Wot, 4096, 2048, 2048, 1,
                                                    nullptr, nullptr, nullptr, nullptr, nullptr,
                                                    (float*)d_out);
}

// Round 4
// 395.125 us; speedup vs baseline: 1.9373x; 1.1256x over previous
//
#include <hip/hip_runtime.h>

typedef unsigned short u16;
typedef unsigned int u32;
typedef __bf16 bf16x8 __attribute__((ext_vector_type(8)));
typedef float f32x4 __attribute__((ext_vector_type(4)));

// ---------- helpers ----------
__device__ __forceinline__ u16 f2bf(float f) {
  union { float f; u32 u; } v; v.f = f;
  u32 r = v.u + 0x7fffu + ((v.u >> 16) & 1u);   // RNE
  return (u16)(r >> 16);
}

__device__ __forceinline__ bf16x8 ldb128(const u16* p) {
  return *reinterpret_cast<const bf16x8*>(p);
}

__device__ __forceinline__ f32x4 mfma16(bf16x8 a, bf16x8 b, f32x4 c) {
  return __builtin_amdgcn_mfma_f32_16x16x32_bf16(a, b, c, 0, 0, 0);
}

typedef const __attribute__((address_space(1))) u32* gas_p;
typedef __attribute__((address_space(3))) u32* las_p;
// async global->LDS, 16B per lane; lds dst is wave-uniform base + lane*16B
__device__ __forceinline__ void gld_lds16(const void* g, void* l) {
  __builtin_amdgcn_global_load_lds((gas_p)(unsigned long long)g,
                                   (las_p)(u32)(unsigned long long)l, 16, 0, 0);
}

// ---------- convert f32 -> bf16 (vectorized) ----------
__global__ __launch_bounds__(256) void cvt_f32_bf16(const float4* __restrict__ in,
                                                    uint2* __restrict__ out) {
  int i = blockIdx.x * 256 + threadIdx.x;
  float4 v = in[i];
  uint2 r;
  r.x = (u32)f2bf(v.x) | ((u32)f2bf(v.y) << 16);
  r.y = (u32)f2bf(v.z) | ((u32)f2bf(v.w) << 16);
  out[i] = r;
}

// ---------- transpose + convert: in[R][C] f32 -> out[C][R] bf16 ----------
__global__ __launch_bounds__(256) void transp_cvt(const float* __restrict__ in,
                                                  u16* __restrict__ out, int R, int C) {
  __shared__ float tile[32][33];
  int n0 = blockIdx.x * 32, k0 = blockIdx.y * 32;
  int tx = threadIdx.x, ty = threadIdx.y;   // block (32,8)
#pragma unroll
  for (int i = 0; i < 32; i += 8) tile[ty + i][tx] = in[(k0 + ty + i) * C + n0 + tx];
  __syncthreads();
#pragma unroll
  for (int i = 0; i < 32; i += 8) out[(n0 + ty + i) * R + k0 + tx] = f2bf(tile[tx][ty + i]);
}

// ---------- deep-pipelined GEMM: C = A[M][K] @ Bt[N][K]^T ----------
// BM=256 rows, BK=64, 8 waves (512 thr). Double-buffered swizzled LDS,
// counted vmcnt (T4), XOR-swizzle (T2), setprio (T5), XCD swizzle (T1).
// MODE 0: QKV epilogue (RoPE on Q/K, V transposed). MODE 1: plain f32 store.
template<int BN, int WM, int WN, int MODE, int LOADS>
__global__ __launch_bounds__(512) void gemm_pipe(
    const u16* __restrict__ A, const u16* __restrict__ Bt,
    int M, int N, int K,
    const float* __restrict__ cosb, const float* __restrict__ sinb,
    u16* __restrict__ Qb, u16* __restrict__ Kb, u16* __restrict__ Vt,
    float* __restrict__ outf) {
  constexpr int BM = 256;
  constexpr int WTM = BM / WM;            // per-wave M (128 or 64)
  constexpr int WTN = BN / WN;            // per-wave N (64)
  constexpr int MR = WTM / 16;            // 8 or 4
  constexpr int NR = WTN / 16;            // 4
  constexpr int PA = (BM / 8) / 8;        // A chunks per wave (4)
  constexpr int PB = (BN / 8) / 8;        // B chunks per wave (4 or 2)

  __shared__ u16 As[2][BM][64];           // rows 128B, swizzled via source
  __shared__ u16 Bs[2][BN][64];

  const int tid = threadIdx.x;
  const int wv = tid >> 6, lane = tid & 63;
  const int c = lane & 15, g = lane >> 4;
  const int swz = (c & 7) << 4;           // byte-XOR for frag reads

  // XCD-aware bijective block swizzle (nwg % 8 == 0 for both instantiations)
  const int nwg = gridDim.x * gridDim.y;
  const int obid = blockIdx.y * gridDim.x + blockIdx.x;
  const int bid = (obid & 7) * (nwg >> 3) + (obid >> 3);
  const int m0 = (bid / gridDim.x) * BM;
  const int n0 = (bid % gridDim.x) * BN;

  const int wm = wv / WN, wn = wv % WN;

  // staging geometry: chunk = 8 rows x 64 elem (1 KB). lane l -> row +l>>3,
  // source col pre-swizzled so linear LDS + XOR'd read is the identity.
  const int lr = lane >> 3;
  const int lc8 = ((lane & 7) ^ lr) * 8;  // element offset, 16B aligned

  f32x4 acc[MR][NR] = {};
  const int NT = K >> 6;                  // K/64 tiles

  auto STAGE = [&](int buf, int t) {
    const int k0 = t * 64;
#pragma unroll
    for (int i = 0; i < PA; i++) {
      const int ch = wv * PA + i;
      gld_lds16(A + (long)(m0 + ch * 8 + lr) * K + k0 + lc8, &As[buf][ch * 8][0]);
    }
#pragma unroll
    for (int i = 0; i < PB; i++) {
      const int ch = wv * PB + i;
      gld_lds16(Bt + (long)(n0 + ch * 8 + lr) * K + k0 + lc8, &Bs[buf][ch * 8][0]);
    }
  };

  auto COMPUTE = [&](int buf) {
#pragma unroll
    for (int kk = 0; kk < 2; kk++) {
      bf16x8 af[MR], bfr[NR];
#pragma unroll
      for (int i = 0; i < MR; i++)
        af[i] = ldb128(&As[buf][wm * WTM + i * 16 + c][((kk * 64 + g * 16) ^ swz) >> 1]);
#pragma unroll
      for (int j = 0; j < NR; j++)
        bfr[j] = ldb128(&Bs[buf][wn * WTN + j * 16 + c][((kk * 64 + g * 16) ^ swz) >> 1]);
      __builtin_amdgcn_s_setprio(1);
#pragma unroll
      for (int i = 0; i < MR; i++)
#pragma unroll
        for (int j = 0; j < NR; j++)
          acc[i][j] = mfma16(af[i], bfr[j], acc[i][j]);
      __builtin_amdgcn_s_setprio(0);
    }
  };

  STAGE(0, 0);
  for (int t = 0; t < NT - 1; ++t) {
    STAGE((t + 1) & 1, t + 1);                       // issue next tile (stays in flight)
    asm volatile("s_waitcnt vmcnt(%0)" :: "i"(LOADS) : "memory");  // tile t landed (mine)
    __builtin_amdgcn_s_barrier();                    // tile t landed (all waves)
    __builtin_amdgcn_sched_barrier(0);
    COMPUTE(t & 1);
    __builtin_amdgcn_sched_barrier(0);
    asm volatile("" ::: "memory");
    __builtin_amdgcn_s_barrier();                    // all done reading buf[t&1]
  }
  asm volatile("s_waitcnt vmcnt(0)" ::: "memory");
  __builtin_amdgcn_s_barrier();
  COMPUTE((NT - 1) & 1);

  // ---------- epilogue ----------
  const float inv_sqrt_hd = 0.08838834764831845f;
#pragma unroll
  for (int i = 0; i < MR; i++) {
#pragma unroll
    for (int j = 0; j < NR; j++) {
      const int ncol = n0 + wn * WTN + j * 16 + c;
#pragma unroll
      for (int r = 0; r < 4; r++) {
        const int m = m0 + wm * WTM + i * 16 + g * 4 + r;
        float val = acc[i][j][r];
        if (MODE == 1) {
          outf[(long)m * N + ncol] = val;
          continue;
        }
        const int s = m & 2047;
        if (ncol < 2048) {              // Q: RoPE + 1/sqrt(hd), bf16
          const int d = ncol & 127;
          float ct = cosb[s * 128 + d], st = sinb[s * 128 + d];
          float pr = __shfl_xor(val, 1, 64);
          float rot = (ncol & 1) ? pr : -pr;
          Qb[m * 2048 + ncol] = f2bf((val * ct + rot * st) * inv_sqrt_hd);
        } else if (ncol < 2560) {       // K: RoPE, bf16
          const int d = ncol & 127;
          float ct = cosb[s * 128 + d], st = sinb[s * 128 + d];
          float pr = __shfl_xor(val, 1, 64);
          float rot = (ncol & 1) ? pr : -pr;
          Kb[m * 512 + (ncol - 2048)] = f2bf(val * ct + rot * st);
        } else {                        // V: store transposed Vt[bkvh*128+d][s]
          const int bb = m >> 11;
          Vt[(bb * 512 + (ncol - 2560)) * 2048 + s] = f2bf(val);
        }
      }
    }
  }
}

// ---------- flash attention v2: LDS-staged K/V (XOR-swizzled), causal, GQA ----------
__global__ __launch_bounds__(256) void attn_fwd(
    const u16* __restrict__ Qb, const u16* __restrict__ Kb,
    const u16* __restrict__ Vt, u16* __restrict__ attnb) {
  __shared__ u16 Ks[64 * 128];    // [key][d], rows XOR-swizzled
  __shared__ u16 Vs[128 * 64];    // [d][key], same swizzle
  __shared__ u16 Pl[4][16 * 64];  // per-wave P [q][k], same swizzle
  const int tid = threadIdx.x;
  const int wv = tid >> 6, lane = tid & 63;
  const int c = lane & 15, g = lane >> 4;
  const int qt = 31 - (int)blockIdx.x;         // heavy blocks dispatch first
  const int h = blockIdx.y, b = blockIdx.z;
  const int kvh = h >> 2;
  const int q = qt * 64 + wv * 16 + c;
  const int swz = (c & 7) << 4;

  bf16x8 qf[4];
  const u16* qptr = Qb + ((b << 11) + q) * 2048 + h * 128 + g * 8;
#pragma unroll
  for (int dc = 0; dc < 4; dc++) qf[dc] = ldb128(qptr + dc * 32);

  f32x4 oacc[8] = {};
  float m_run = -1e30f, l_run = 0.f;

  const int krow = wv * 16 + g;
  const int vrow = wv * 32 + (lane >> 3);
  const u16* Kg = Kb + kvh * 128;
  const u16* Vg = Vt + (b * 512 + kvh * 128) * 2048;

  for (int kt = 0; kt <= qt; kt++) {
    const int k0 = kt * 64;
#pragma unroll
    for (int i = 0; i < 4; i++) {
      const int r = krow + i * 4;
      gld_lds16(Kg + ((long)(b * 2048 + k0 + r)) * 512 + ((c ^ (r & 7)) * 8),
                &Ks[(wv * 4 + i) * 512]);
    }
#pragma unroll
    for (int i = 0; i < 4; i++) {
      const int r = vrow + i * 8;
      gld_lds16(Vg + (long)r * 2048 + k0 + (((lane & 7) ^ (r & 7)) * 8),
                &Vs[(wv * 4 + i) * 512]);
    }
    __syncthreads();

    f32x4 t[4] = {};
#pragma unroll
    for (int kf = 0; kf < 4; kf++) {
#pragma unroll
      for (int dc = 0; dc < 4; dc++) {
        const bf16x8 kfr = ldb128(&Ks[(kf * 16 + c) * 128 + (((dc * 64 + g * 16) ^ swz) >> 1)]);
        t[kf] = mfma16(kfr, qf[dc], t[kf]);
      }
    }
    if (kt == qt) {
#pragma unroll
      for (int kf = 0; kf < 4; kf++)
#pragma unroll
        for (int r = 0; r < 4; r++)
          if (k0 + kf * 16 + g * 4 + r > q) t[kf][r] = -1e30f;
    }
    float pmax = -1e30f;
#pragma unroll
    for (int kf = 0; kf < 4; kf++)
#pragma unroll
      for (int r = 0; r < 4; r++) pmax = fmaxf(pmax, t[kf][r]);
    pmax = fmaxf(pmax, __shfl_xor(pmax, 16, 64));
    pmax = fmaxf(pmax, __shfl_xor(pmax, 32, 64));
    const float mnew = fmaxf(m_run, pmax);
    const float scale = __expf(m_run - mnew);
    float psum = 0.f;
#pragma unroll
    for (int kf = 0; kf < 4; kf++) {
      float p0 = __expf(t[kf][0] - mnew), p1 = __expf(t[kf][1] - mnew);
      float p2 = __expf(t[kf][2] - mnew), p3 = __expf(t[kf][3] - mnew);
      psum += (p0 + p1) + (p2 + p3);
      u32* pw = (u32*)&Pl[wv][c * 64 + (((kf * 32 + g * 8) ^ swz) >> 1)];
      pw[0] = (u32)f2bf(p0) | ((u32)f2bf(p1) << 16);
      pw[1] = (u32)f2bf(p2) | ((u32)f2bf(p3) << 16);
    }
    psum += __shfl_xor(psum, 16, 64);
    psum += __shfl_xor(psum, 32, 64);
    l_run = l_run * scale + psum;
    m_run = mnew;
#pragma unroll
    for (int df = 0; df < 8; df++) oacc[df] *= scale;

    const bf16x8 pb0 = ldb128(&Pl[wv][c * 64 + (((g * 16) ^ swz) >> 1)]);
    const bf16x8 pb1 = ldb128(&Pl[wv][c * 64 + (((64 + g * 16) ^ swz) >> 1)]);
#pragma unroll
    for (int df = 0; df < 8; df++) {
      const int vb = (df * 16 + c) * 64;
      oacc[df] = mfma16(ldb128(&Vs[vb + (((g * 16) ^ swz) >> 1)]), pb0, oacc[df]);
      oacc[df] = mfma16(ldb128(&Vs[vb + (((64 + g * 16) ^ swz) >> 1)]), pb1, oacc[df]);
    }
    __syncthreads();
  }

  const float rinv = 1.f / l_run;
  const int obase = ((b << 11) + q) * 2048 + h * 128;
#pragma unroll
  for (int df = 0; df < 8; df++)
#pragma unroll
    for (int r = 0; r < 4; r++)
      attnb[obase + df * 16 + g * 4 + r] = f2bf(oacc[df][r] * rinv);
}

// ---------- launch ----------
extern "C" void kernel_launch(void* const* d_in, const int* in_sizes, int n_in,
                              void* d_out, int out_size, void* d_ws, size_t ws_size,
                              hipStream_t stream) {
  const float* X    = (const float*)d_in[0];  // (2,2048,2048)
  const float* cosb = (const float*)d_in[1];  // (2048,128)
  const float* sinb = (const float*)d_in[2];
  const float* Wq   = (const float*)d_in[3];  // (2048,2048)
  const float* Wk   = (const float*)d_in[4];  // (2048,512)
  const float* Wv   = (const float*)d_in[5];
  const float* Wo   = (const float*)d_in[6];  // (2048,2048)

  char* ws = (char*)d_ws;
  u16* Xb    = (u16*)(ws);                       // 4096x2048 bf16 : 16 MB
  u16* Wt    = (u16*)(ws + 16777216);            // 3072x2048 bf16 : 12 MB (Wq^T|Wk^T|Wv^T)
  u16* Wot   = (u16*)(ws + 29360128);            // 2048x2048 bf16 : 8 MB
  u16* Qb    = (u16*)(ws + 37748736);            // 4096x2048 bf16 : 16 MB
  u16* Kb    = (u16*)(ws + 54525952);            // 4096x512  bf16 : 4 MB
  u16* Vt    = (u16*)(ws + 58720256);            // 1024x2048 bf16 : 4 MB
  u16* attnb = Xb;                               // alias: Xb dead after QKV GEMM

  // 1) convert hidden to bf16
  cvt_f32_bf16<<<dim3(8192), dim3(256), 0, stream>>>((const float4*)X, (uint2*)Xb);
  // 2) transpose+convert weights -> [N][K] bf16
  transp_cvt<<<dim3(64, 64), dim3(32, 8), 0, stream>>>(Wq, Wt, 2048, 2048);
  transp_cvt<<<dim3(16, 64), dim3(32, 8), 0, stream>>>(Wk, Wt + 2048 * 2048, 2048, 512);
  transp_cvt<<<dim3(16, 64), dim3(32, 8), 0, stream>>>(Wv, Wt + 2560 * 2048, 2048, 512);
  transp_cvt<<<dim3(64, 64), dim3(32, 8), 0, stream>>>(Wo, Wot, 2048, 2048);
  // 3) fused QKV GEMM + RoPE epilogue (256x256 tile, 2x4 waves, 8 loads/tile)
  gemm_pipe<256, 2, 4, 0, 8><<<dim3(12, 16), dim3(512), 0, stream>>>(
      Xb, Wt, 4096, 3072, 2048, cosb, sinb, Qb, Kb, Vt, nullptr);
  // 4) causal GQA flash attention
  attn_fwd<<<dim3(32, 16, 2), dim3(256), 0, stream>>>(Qb, Kb, Vt, attnb);
  // 5) output GEMM -> f32 d_out (256x128 tile, 4x2 waves, 6 loads/tile)
  gemm_pipe<128, 4, 2, 1, 6><<<dim3(16, 16), dim3(512), 0, stream>>>(
      attnb, Wot, 4096, 2048, 2048, nullptr, nullptr, nullptr, nullptr, nullptr,
      (float*)d_out);
}

// Round 5
// 331.674 us; speedup vs baseline: 2.3079x; 1.1913x over previous
//
#include <hip/hip_runtime.h>

typedef unsigned short u16;
typedef unsigned int u32;
typedef __bf16 bf16x8 __attribute__((ext_vector_type(8)));
typedef float f32x4 __attribute__((ext_vector_type(4)));

// ---------- helpers ----------
__device__ __forceinline__ u16 f2bf(float f) {
  union { float f; u32 u; } v; v.f = f;
  u32 r = v.u + 0x7fffu + ((v.u >> 16) & 1u);   // RNE
  return (u16)(r >> 16);
}

__device__ __forceinline__ u32 pack2(float a, float b) {   // 2xbf16 (RNE via native cvt)
  union { __bf16 h[2]; u32 u; } x;
  x.h[0] = (__bf16)a; x.h[1] = (__bf16)b;
  return x.u;
}

__device__ __forceinline__ bf16x8 ldb128(const u16* p) {
  return *reinterpret_cast<const bf16x8*>(p);
}

__device__ __forceinline__ f32x4 mfma16(bf16x8 a, bf16x8 b, f32x4 c) {
  return __builtin_amdgcn_mfma_f32_16x16x32_bf16(a, b, c, 0, 0, 0);
}

typedef const __attribute__((address_space(1))) u32* gas_p;
typedef __attribute__((address_space(3))) u32* las_p;
// async global->LDS, 16B per lane; lds dst is wave-uniform base + lane*16B
__device__ __forceinline__ void gld_lds16(const void* g, void* l) {
  __builtin_amdgcn_global_load_lds((gas_p)(unsigned long long)g,
                                   (las_p)(u32)(unsigned long long)l, 16, 0, 0);
}

// ---------- convert f32 -> bf16 (vectorized) ----------
__global__ __launch_bounds__(256) void cvt_f32_bf16(const float4* __restrict__ in,
                                                    uint2* __restrict__ out) {
  int i = blockIdx.x * 256 + threadIdx.x;
  float4 v = in[i];
  uint2 r;
  r.x = (u32)f2bf(v.x) | ((u32)f2bf(v.y) << 16);
  r.y = (u32)f2bf(v.z) | ((u32)f2bf(v.w) << 16);
  out[i] = r;
}

// ---------- transpose + convert: in[R][C] f32 -> out[C][R] bf16 ----------
__global__ __launch_bounds__(256) void transp_cvt(const float* __restrict__ in,
                                                  u16* __restrict__ out, int R, int C) {
  __shared__ float tile[32][33];
  int n0 = blockIdx.x * 32, k0 = blockIdx.y * 32;
  int tx = threadIdx.x, ty = threadIdx.y;   // block (32,8)
#pragma unroll
  for (int i = 0; i < 32; i += 8) tile[ty + i][tx] = in[(k0 + ty + i) * C + n0 + tx];
  __syncthreads();
#pragma unroll
  for (int i = 0; i < 32; i += 8) out[(n0 + ty + i) * R + k0 + tx] = f2bf(tile[tx][ty + i]);
}

// ---------- deep-pipelined GEMM: C = A[M][K] @ Bt[N][K]^T ----------
// BM=256 rows, BK=64, 8 waves (512 thr). Double-buffered swizzled LDS,
// counted vmcnt (T4), XOR-swizzle (T2), setprio (T5), XCD swizzle (T1).
// MODE 0: QKV epilogue (RoPE on Q/K, V transposed). MODE 1: plain f32 store.
template<int BN, int WM, int WN, int MODE, int LOADS>
__global__ __launch_bounds__(512) void gemm_pipe(
    const u16* __restrict__ A, const u16* __restrict__ Bt,
    int M, int N, int K,
    const float* __restrict__ cosb, const float* __restrict__ sinb,
    u16* __restrict__ Qb, u16* __restrict__ Kb, u16* __restrict__ Vt,
    float* __restrict__ outf) {
  constexpr int BM = 256;
  constexpr int WTM = BM / WM;            // per-wave M
  constexpr int WTN = BN / WN;            // per-wave N
  constexpr int MR = WTM / 16;
  constexpr int NR = WTN / 16;
  constexpr int PA = (BM / 8) / 8;        // A chunks per wave
  constexpr int PB = (BN / 8) / 8;        // B chunks per wave

  __shared__ u16 As[2][BM][64];           // rows 128B, swizzled via source
  __shared__ u16 Bs[2][BN][64];

  const int tid = threadIdx.x;
  const int wv = tid >> 6, lane = tid & 63;
  const int c = lane & 15, g = lane >> 4;
  const int swz = (c & 7) << 4;           // byte-XOR for frag reads

  // XCD-aware bijective block swizzle (nwg % 8 == 0 for both instantiations)
  const int nwg = gridDim.x * gridDim.y;
  const int obid = blockIdx.y * gridDim.x + blockIdx.x;
  const int bid = (obid & 7) * (nwg >> 3) + (obid >> 3);
  const int m0 = (bid / gridDim.x) * BM;
  const int n0 = (bid % gridDim.x) * BN;

  const int wm = wv / WN, wn = wv % WN;

  const int lr = lane >> 3;
  const int lc8 = ((lane & 7) ^ lr) * 8;  // pre-swizzled source col (16B unit)

  f32x4 acc[MR][NR] = {};
  const int NT = K >> 6;                  // K/64 tiles

  auto STAGE = [&](int buf, int t) {
    const int k0 = t * 64;
#pragma unroll
    for (int i = 0; i < PA; i++) {
      const int ch = wv * PA + i;
      gld_lds16(A + (long)(m0 + ch * 8 + lr) * K + k0 + lc8, &As[buf][ch * 8][0]);
    }
#pragma unroll
    for (int i = 0; i < PB; i++) {
      const int ch = wv * PB + i;
      gld_lds16(Bt + (long)(n0 + ch * 8 + lr) * K + k0 + lc8, &Bs[buf][ch * 8][0]);
    }
  };

  auto COMPUTE = [&](int buf) {
#pragma unroll
    for (int kk = 0; kk < 2; kk++) {
      bf16x8 af[MR], bfr[NR];
#pragma unroll
      for (int i = 0; i < MR; i++)
        af[i] = ldb128(&As[buf][wm * WTM + i * 16 + c][((kk * 64 + g * 16) ^ swz) >> 1]);
#pragma unroll
      for (int j = 0; j < NR; j++)
        bfr[j] = ldb128(&Bs[buf][wn * WTN + j * 16 + c][((kk * 64 + g * 16) ^ swz) >> 1]);
      __builtin_amdgcn_s_setprio(1);
#pragma unroll
      for (int i = 0; i < MR; i++)
#pragma unroll
        for (int j = 0; j < NR; j++)
          acc[i][j] = mfma16(af[i], bfr[j], acc[i][j]);
      __builtin_amdgcn_s_setprio(0);
    }
  };

  STAGE(0, 0);
  for (int t = 0; t < NT - 1; ++t) {
    STAGE((t + 1) & 1, t + 1);                       // next tile stays in flight
    asm volatile("s_waitcnt vmcnt(%0)" :: "i"(LOADS) : "memory");  // tile t landed
    __builtin_amdgcn_s_barrier();
    __builtin_amdgcn_sched_barrier(0);
    COMPUTE(t & 1);
    __builtin_amdgcn_sched_barrier(0);
    asm volatile("" ::: "memory");
    __builtin_amdgcn_s_barrier();                    // all waves done with buf
  }
  asm volatile("s_waitcnt vmcnt(0)" ::: "memory");
  __builtin_amdgcn_s_barrier();
  COMPUTE((NT - 1) & 1);

  // ---------- epilogue ----------
  // Q absorbs 1/sqrt(hd) * log2(e) so attention can use exp2 directly.
  const float q_scale = 0.12751743f;
#pragma unroll
  for (int i = 0; i < MR; i++) {
#pragma unroll
    for (int j = 0; j < NR; j++) {
      const int ncol = n0 + wn * WTN + j * 16 + c;
      if (MODE == 1) {
#pragma unroll
        for (int r = 0; r < 4; r++) {
          const int m = m0 + wm * WTM + i * 16 + g * 4 + r;
          outf[(long)m * N + ncol] = acc[i][j][r];
        }
        continue;
      }
      if (ncol < 2560) {                // Q or K: RoPE
#pragma unroll
        for (int r = 0; r < 4; r++) {
          const int m = m0 + wm * WTM + i * 16 + g * 4 + r;
          const int s = m & 2047;
          const int d = ncol & 127;
          float val = acc[i][j][r];
          float ct = cosb[s * 128 + d], st = sinb[s * 128 + d];
          float pr = __shfl_xor(val, 1, 64);
          float rot = (ncol & 1) ? pr : -pr;
          float rp = val * ct + rot * st;
          if (ncol < 2048) Qb[m * 2048 + ncol] = f2bf(rp * q_scale);
          else             Kb[m * 512 + (ncol - 2048)] = f2bf(rp);
        }
      } else {                          // V: store transposed Vt[bkvh*128+d][s]
        const int m_base = m0 + wm * WTM + i * 16 + g * 4;
        const int bb = m_base >> 11;
        const int srow = m_base & 2047; // contiguous over r
        uint2 pv;
        pv.x = pack2(acc[i][j][0], acc[i][j][1]);
        pv.y = pack2(acc[i][j][2], acc[i][j][3]);
        *(uint2*)&Vt[(bb * 512 + (ncol - 2560)) * 2048 + srow] = pv;
      }
    }
  }
}

// ---------- flash attention v3: 2 q-sets/wave, double-buffered K/V, exp2 ----------
// Block: 4 waves x 32 q-rows = 128 q. KV tile 64. K/V XOR-swizzled via source.
__global__ __launch_bounds__(256, 2) void attn_fwd(
    const u16* __restrict__ Qb, const u16* __restrict__ Kb,
    const u16* __restrict__ Vt, u16* __restrict__ attnb) {
  __shared__ u16 Ks[2][64 * 128];       // [key][d] swizzled, double-buffered
  __shared__ u16 Vs[2][128 * 64];       // [d][key] swizzled
  __shared__ u16 Pl[4][2][16 * 64];     // per-wave, per-set P [q][k] swizzled
  const int tid = threadIdx.x;
  const int wv = tid >> 6, lane = tid & 63;
  const int c = lane & 15, g = lane >> 4;
  const int qt = 15 - (int)blockIdx.x;  // heavy blocks first
  const int h = blockIdx.y, b = blockIdx.z;
  const int kvh = h >> 2;
  const int qbase = qt * 128 + wv * 32; // +set*16+c
  const int swz = (c & 7) << 4;

  // Q fragments for both sets (Q already scaled by log2e/sqrt(hd))
  bf16x8 qf0[4], qf1[4];
  {
    const u16* qp0 = Qb + ((b << 11) + qbase + c) * 2048 + h * 128 + g * 8;
#pragma unroll
    for (int dc = 0; dc < 4; dc++) qf0[dc] = ldb128(qp0 + dc * 32);
    const u16* qp1 = qp0 + 16 * 2048;
#pragma unroll
    for (int dc = 0; dc < 4; dc++) qf1[dc] = ldb128(qp1 + dc * 32);
  }

  f32x4 oacc0[8] = {}, oacc1[8] = {};
  float m0r = -1e30f, l0r = 0.f, m1r = -1e30f, l1r = 0.f;

  const int krow = wv * 16 + g;
  const int vrow = wv * 32 + (lane >> 3);
  const u16* Kg = Kb + kvh * 128;
  const u16* Vg = Vt + (b * 512 + kvh * 128) * 2048;
  const int NKV = 2 * qt + 2;

  auto STAGE = [&](int buf, int t) {
    const int k0 = t * 64;
#pragma unroll
    for (int i = 0; i < 4; i++) {
      const int r = krow + i * 4;
      gld_lds16(Kg + ((long)(b * 2048 + k0 + r)) * 512 + ((c ^ (r & 7)) * 8),
                &Ks[buf][(wv * 4 + i) * 512]);
    }
#pragma unroll
    for (int i = 0; i < 4; i++) {
      const int r = vrow + i * 8;
      gld_lds16(Vg + (long)r * 2048 + k0 + (((lane & 7) ^ (r & 7)) * 8),
                &Vs[buf][(wv * 4 + i) * 512]);
    }
  };

  STAGE(0, 0);
  for (int kt = 0; kt < NKV; kt++) {
    const int buf = kt & 1;
    const int k0 = kt * 64;
    if (kt + 1 < NKV) {
      STAGE(buf ^ 1, kt + 1);
      asm volatile("s_waitcnt vmcnt(8)" ::: "memory");
    } else {
      asm volatile("s_waitcnt vmcnt(0)" ::: "memory");
    }
    __builtin_amdgcn_s_barrier();
    __builtin_amdgcn_sched_barrier(0);

    // ---- S^T for both q-sets, sharing K-fragment reads ----
    f32x4 t0[4] = {}, t1[4] = {};
#pragma unroll
    for (int kf = 0; kf < 4; kf++) {
#pragma unroll
      for (int dc = 0; dc < 4; dc++) {
        const bf16x8 kfr =
            ldb128(&Ks[buf][(kf * 16 + c) * 128 + (((dc * 64 + g * 16) ^ swz) >> 1)]);
        t0[kf] = mfma16(kfr, qf0[dc], t0[kf]);
        t1[kf] = mfma16(kfr, qf1[dc], t1[kf]);
      }
    }
    if (kt >= NKV - 2) {                 // diagonal region: causal mask
      const int q0 = qbase + c, q1 = q0 + 16;
#pragma unroll
      for (int kf = 0; kf < 4; kf++)
#pragma unroll
        for (int r = 0; r < 4; r++) {
          const int key = k0 + kf * 16 + g * 4 + r;
          if (key > q0) t0[kf][r] = -1e30f;
          if (key > q1) t1[kf][r] = -1e30f;
        }
    }
    // ---- online softmax per set (exp2 domain) ----
#pragma unroll
    for (int s = 0; s < 2; s++) {
      f32x4* t = s ? t1 : t0;
      float& mr = s ? m1r : m0r;
      float& lr_ = s ? l1r : l0r;
      f32x4* oa = s ? oacc1 : oacc0;
      float pmax = -1e30f;
#pragma unroll
      for (int kf = 0; kf < 4; kf++)
#pragma unroll
        for (int r = 0; r < 4; r++) pmax = fmaxf(pmax, t[kf][r]);
      pmax = fmaxf(pmax, __shfl_xor(pmax, 16, 64));
      pmax = fmaxf(pmax, __shfl_xor(pmax, 32, 64));
      const float mnew = fmaxf(mr, pmax);
      const float scale = __builtin_amdgcn_exp2f(mr - mnew);
      float psum = 0.f;
#pragma unroll
      for (int kf = 0; kf < 4; kf++) {
        float p0 = __builtin_amdgcn_exp2f(t[kf][0] - mnew);
        float p1 = __builtin_amdgcn_exp2f(t[kf][1] - mnew);
        float p2 = __builtin_amdgcn_exp2f(t[kf][2] - mnew);
        float p3 = __builtin_amdgcn_exp2f(t[kf][3] - mnew);
        psum += (p0 + p1) + (p2 + p3);
        u32* pw = (u32*)&Pl[wv][s][c * 64 + (((kf * 32 + g * 8) ^ swz) >> 1)];
        pw[0] = pack2(p0, p1);
        pw[1] = pack2(p2, p3);
      }
      psum += __shfl_xor(psum, 16, 64);
      psum += __shfl_xor(psum, 32, 64);
      lr_ = lr_ * scale + psum;
      mr = mnew;
#pragma unroll
      for (int df = 0; df < 8; df++) oa[df] *= scale;
    }

    // ---- PV for both sets, sharing V-fragment reads ----
    const bf16x8 pa0 = ldb128(&Pl[wv][0][c * 64 + (((g * 16) ^ swz) >> 1)]);
    const bf16x8 pa1 = ldb128(&Pl[wv][0][c * 64 + (((64 + g * 16) ^ swz) >> 1)]);
    const bf16x8 pb0 = ldb128(&Pl[wv][1][c * 64 + (((g * 16) ^ swz) >> 1)]);
    const bf16x8 pb1 = ldb128(&Pl[wv][1][c * 64 + (((64 + g * 16) ^ swz) >> 1)]);
#pragma unroll
    for (int df = 0; df < 8; df++) {
      const int vb = (df * 16 + c) * 64;
      const bf16x8 v0 = ldb128(&Vs[buf][vb + (((g * 16) ^ swz) >> 1)]);
      const bf16x8 v1 = ldb128(&Vs[buf][vb + (((64 + g * 16) ^ swz) >> 1)]);
      oacc0[df] = mfma16(v0, pa0, oacc0[df]);
      oacc0[df] = mfma16(v1, pa1, oacc0[df]);
      oacc1[df] = mfma16(v0, pb0, oacc1[df]);
      oacc1[df] = mfma16(v1, pb1, oacc1[df]);
    }
    __builtin_amdgcn_sched_barrier(0);
    asm volatile("" ::: "memory");
    __builtin_amdgcn_s_barrier();
  }

  const float ri0 = 1.f / l0r, ri1 = 1.f / l1r;
  const long ob0 = ((long)(b << 11) + qbase + c) * 2048 + h * 128 + g * 4;
#pragma unroll
  for (int df = 0; df < 8; df++) {
    uint2 o0, o1;
    o0.x = pack2(oacc0[df][0] * ri0, oacc0[df][1] * ri0);
    o0.y = pack2(oacc0[df][2] * ri0, oacc0[df][3] * ri0);
    o1.x = pack2(oacc1[df][0] * ri1, oacc1[df][1] * ri1);
    o1.y = pack2(oacc1[df][2] * ri1, oacc1[df][3] * ri1);
    *(uint2*)&attnb[ob0 + df * 16] = o0;
    *(uint2*)&attnb[ob0 + 16 * 2048 + df * 16] = o1;
  }
}

// ---------- launch ----------
extern "C" void kernel_launch(void* const* d_in, const int* in_sizes, int n_in,
                              void* d_out, int out_size, void* d_ws, size_t ws_size,
                              hipStream_t stream) {
  const float* X    = (const float*)d_in[0];  // (2,2048,2048)
  const float* cosb = (const float*)d_in[1];  // (2048,128)
  const float* sinb = (const float*)d_in[2];
  const float* Wq   = (const float*)d_in[3];  // (2048,2048)
  const float* Wk   = (const float*)d_in[4];  // (2048,512)
  const float* Wv   = (const float*)d_in[5];
  const float* Wo   = (const float*)d_in[6];  // (2048,2048)

  char* ws = (char*)d_ws;
  u16* Xb    = (u16*)(ws);                       // 4096x2048 bf16 : 16 MB
  u16* Wt    = (u16*)(ws + 16777216);            // 3072x2048 bf16 : 12 MB (Wq^T|Wk^T|Wv^T)
  u16* Wot   = (u16*)(ws + 29360128);            // 2048x2048 bf16 : 8 MB
  u16* Qb    = (u16*)(ws + 37748736);            // 4096x2048 bf16 : 16 MB
  u16* Kb    = (u16*)(ws + 54525952);            // 4096x512  bf16 : 4 MB
  u16* Vt    = (u16*)(ws + 58720256);            // 1024x2048 bf16 : 4 MB
  u16* attnb = Xb;                               // alias: Xb dead after QKV GEMM

  // 1) convert hidden to bf16
  cvt_f32_bf16<<<dim3(8192), dim3(256), 0, stream>>>((const float4*)X, (uint2*)Xb);
  // 2) transpose+convert weights -> [N][K] bf16
  transp_cvt<<<dim3(64, 64), dim3(32, 8), 0, stream>>>(Wq, Wt, 2048, 2048);
  transp_cvt<<<dim3(16, 64), dim3(32, 8), 0, stream>>>(Wk, Wt + 2048 * 2048, 2048, 512);
  transp_cvt<<<dim3(16, 64), dim3(32, 8), 0, stream>>>(Wv, Wt + 2560 * 2048, 2048, 512);
  transp_cvt<<<dim3(64, 64), dim3(32, 8), 0, stream>>>(Wo, Wot, 2048, 2048);
  // 3) fused QKV GEMM + RoPE epilogue (256x192 tile -> 256 blocks, full CU coverage)
  gemm_pipe<192, 2, 4, 0, 7><<<dim3(16, 16), dim3(512), 0, stream>>>(
      Xb, Wt, 4096, 3072, 2048, cosb, sinb, Qb, Kb, Vt, nullptr);
  // 4) causal GQA flash attention (128 q/block, 512 blocks, 2 blocks/CU)
  attn_fwd<<<dim3(16, 16, 2), dim3(256), 0, stream>>>(Qb, Kb, Vt, attnb);
  // 5) output GEMM -> f32 d_out (256x128 tile, 256 blocks)
  gemm_pipe<128, 4, 2, 1, 6><<<dim3(16, 16), dim3(512), 0, stream>>>(
      attnb, Wot, 4096, 2048, 2048, nullptr, nullptr, nullptr, nullptr, nullptr,
      (float*)d_out);
}